// Round 13
// baseline (127.180 us; speedup 1.0000x reference)
//
#include <hip/hip_runtime.h>
#include <math.h>

#define B_ 8
#define T_ 2048
#define C_ 1024
#define H_ 128

#define GM 64            // gemm M-tile
#define GN 128           // gemm N-tile
#define GK 64            // gemm K-tile

typedef __attribute__((ext_vector_type(8))) short s16x8;
typedef __attribute__((ext_vector_type(4))) float f32x4;
typedef __attribute__((ext_vector_type(8))) _Float16 f16x8;
typedef __attribute__((ext_vector_type(4))) _Float16 f16x4;

// ---------------------------------------------------------------------------
// Kernel 0: W prep — transpose W[k][h] (q,k,v) into Wtf[n][k] fp16.
// ---------------------------------------------------------------------------
__global__ __launch_bounds__(256) void wprep(
    const float* __restrict__ Wq, const float* __restrict__ Wk,
    const float* __restrict__ Wv, _Float16* __restrict__ Wtf)
{
    const int n   = blockIdx.x;           // 0..383
    const int mat = n >> 7;
    const int h   = n & 127;
    const float* W = (mat == 0) ? Wq : (mat == 1) ? Wk : Wv;
    for (int k = threadIdx.x; k < C_; k += 256)
        Wtf[(size_t)n * C_ + k] = (_Float16)W[(size_t)k * H_ + h];
}

// ---------------------------------------------------------------------------
// Kernel 1: 2-term fp16 MFMA GEMM (unchanged from round 8).
// ---------------------------------------------------------------------------
__global__ __launch_bounds__(256, 3) void gemm_proj(
    const float* __restrict__ x,
    const _Float16* __restrict__ Wtf,
    const float* __restrict__ bq, const float* __restrict__ bk,
    const float* __restrict__ bv,
    _Float16* __restrict__ qg, _Float16* __restrict__ kg,
    _Float16* __restrict__ vg)
{
    __shared__ _Float16 Ah[GM * GK];      // 8 KB
    __shared__ _Float16 Al[GM * GK];      // 8 KB
    __shared__ _Float16 Bf[GN * GK];      // 16 KB

    const int tid  = threadIdx.x;
    const int my   = blockIdx.y;
    const long m0  = (long)blockIdx.x * GM;
    const int lane = tid & 63;
    const int w    = tid >> 6;
    const int wr   = w >> 1, wc = w & 1;
    const int lg   = lane >> 4, lc = lane & 15;

    float4 xr[4];

    #define LOAD_X(k0)                                                        \
        _Pragma("unroll")                                                     \
        for (int it = 0; it < 4; ++it) {                                      \
            const int i  = tid + it * 256;                                    \
            const int r  = i >> 4;                                            \
            const int k4 = i & 15;                                            \
            xr[it] = *(const float4*)&x[(m0 + r) * C_ + (k0) + k4 * 4];       \
        }

    #define STORE_LDS(k0)                                                     \
        _Pragma("unroll")                                                     \
        for (int it = 0; it < 4; ++it) {                                      \
            const int i  = tid + it * 256;                                    \
            const int r  = i >> 4;                                            \
            const int k4 = i & 15;                                            \
            f16x4 hi4, lo4;                                                   \
            _Pragma("unroll")                                                 \
            for (int j = 0; j < 4; ++j) {                                     \
                const float f = ((const float*)&xr[it])[j];                   \
                const _Float16 h16 = (_Float16)f;                             \
                hi4[j] = h16;                                                 \
                lo4[j] = (_Float16)(f - (float)h16);                          \
            }                                                                 \
            const int off = r * 64 + (((k4 >> 1) ^ (r & 7)) << 3)             \
                          + ((k4 & 1) << 2);                                  \
            *(f16x4*)&Ah[off] = hi4;                                          \
            *(f16x4*)&Al[off] = lo4;                                          \
        }                                                                     \
        _Pragma("unroll")                                                     \
        for (int it = 0; it < 4; ++it) {                                      \
            const int i = tid + it * 256;                                     \
            const int r = i >> 3;                                             \
            const int s = i & 7;                                              \
            const size_t g = (size_t)(my * GN + r) * C_ + (k0) + s * 8;       \
            const int off = r * 64 + ((s ^ (r & 7)) << 3);                    \
            *(f16x8*)&Bf[off] = *(const f16x8*)&Wtf[g];                       \
        }

    f32x4 acc[2][4];
    #pragma unroll
    for (int m = 0; m < 2; ++m)
        #pragma unroll
        for (int n = 0; n < 4; ++n) acc[m][n] = (f32x4){0.f, 0.f, 0.f, 0.f};

    LOAD_X(0);
    STORE_LDS(0);
    __syncthreads();

    for (int kt = 0; kt < C_ / GK; ++kt) {
        if (kt < C_ / GK - 1) LOAD_X((kt + 1) * GK);

        #pragma unroll
        for (int kc = 0; kc < 2; ++kc) {
            f16x8 afh[2], afl[2], bf[4];
            #pragma unroll
            for (int m = 0; m < 2; ++m) {
                const int r = wr * 32 + m * 16 + lc;
                const int off = r * 64 + ((((kc << 2) + lg) ^ (r & 7)) << 3);
                afh[m] = *(const f16x8*)&Ah[off];
                afl[m] = *(const f16x8*)&Al[off];
            }
            #pragma unroll
            for (int n = 0; n < 4; ++n) {
                const int r = wc * 64 + n * 16 + lc;
                const int off = r * 64 + ((((kc << 2) + lg) ^ (r & 7)) << 3);
                bf[n] = *(const f16x8*)&Bf[off];
            }
            #pragma unroll
            for (int m = 0; m < 2; ++m)
                #pragma unroll
                for (int n = 0; n < 4; ++n) {
                    acc[m][n] = __builtin_amdgcn_mfma_f32_16x16x32_f16(afh[m], bf[n], acc[m][n], 0, 0, 0);
                    acc[m][n] = __builtin_amdgcn_mfma_f32_16x16x32_f16(afl[m], bf[n], acc[m][n], 0, 0, 0);
                }
        }
        __syncthreads();
        if (kt < C_ / GK - 1) {
            STORE_LDS((kt + 1) * GK);
            __syncthreads();
        }
    }

    const float* bias = (my == 0) ? bq : (my == 1) ? bk : bv;
    _Float16* og = (my == 0) ? qg : (my == 1) ? kg : vg;

    #pragma unroll
    for (int n = 0; n < 4; ++n) {
        const int h = wc * 64 + n * 16 + lc;
        const float bv_ = bias[h];
        #pragma unroll
        for (int m = 0; m < 2; ++m) {
            #pragma unroll
            for (int rr = 0; rr < 4; ++rr) {
                const long row = m0 + wr * 32 + m * 16 + lg * 4 + rr;
                og[(size_t)row * H_ + h] = (_Float16)(acc[m][n][rr] + bv_);
            }
        }
    }
}

// ---------------------------------------------------------------------------
// Kernel 1b: vtrans — vg [B][T][H] -> vtg [B][H][T] (fp16 bits via short).
// ---------------------------------------------------------------------------
__global__ __launch_bounds__(256) void vtrans(
    const short* __restrict__ vh, short* __restrict__ vtg)
{
    __shared__ short tbuf[64][72];
    const int b  = blockIdx.z;
    const int t0 = blockIdx.x * 64;
    const int h0 = blockIdx.y * 64;
    const int tid = threadIdx.x;
    const size_t bo  = (size_t)b * T_ * H_;
    const size_t vbo = (size_t)b * H_ * T_;

    #pragma unroll
    for (int it = 0; it < 2; ++it) {
        const int u = tid + it * 256;
        const int r = u >> 3, c8 = u & 7;
        *(s16x8*)&tbuf[r][c8 * 8] =
            *(const s16x8*)&vh[bo + (size_t)(t0 + r) * H_ + h0 + c8 * 8];
    }
    __syncthreads();
    #pragma unroll
    for (int it = 0; it < 2; ++it) {
        const int u = tid + it * 256;
        const int t8 = u >> 6, hr = u & 63;
        s16x8 v;
        #pragma unroll
        for (int j = 0; j < 8; ++j) v[j] = tbuf[t8 * 8 + j][hr];
        *(s16x8*)&vtg[vbo + (size_t)(h0 + hr) * T_ + t0 + t8 * 8] = v;
    }
}

// ---------------------------------------------------------------------------
// Kernel 2: attn_v9 — v6 body + SPLIT-K across blocks (grid 1024).
// Job: rank = wg>>3, b = wg&7; q = rank>>5, r = rank&31:
//   q0: (tile 63-r, half0)  q1: (tile 63-r, half1)
//   q2: (tile r,    half0)  q3: (tile r,    half1)
// CU sees ranks {r, r+32, r+64, r+96} -> constant 33 rounds/CU, 4-way overlap.
// LDS: K only, 64-key dbuf (32 KB). V read direct from global vtg (b64,
// issued at round top, L1/L2-hot). In-register P (K=16 PV). Partial
// (O*f, m, l) written to workspace; attn_merge combines halves.
// ---------------------------------------------------------------------------
__global__ __launch_bounds__(256, 2) void attn_v9(
    const _Float16* __restrict__ qg, const _Float16* __restrict__ kg,
    const _Float16* __restrict__ vtg, float* __restrict__ pO,
    float* __restrict__ pML)
{
    __shared__ __align__(16) short Kbuf[2][64 * 128];   // 32 KB
    float* Ocmb = (float*)&Kbuf[0][0];   // [32][132] floats (aliased)
    float* Mcmb = (float*)&Kbuf[1][2048];// [32][2]   floats (aliased)

    const int tid  = threadIdx.x;
    const int lane = tid & 63;
    const int w    = tid >> 6;
    const int rg   = w >> 1;
    const int kp   = w & 1;
    const int lg   = lane >> 4;
    const int lc   = lane & 15;
    const int wg   = blockIdx.x;          // 0..1023
    const int rank = wg >> 3;
    const int b    = wg & 7;
    const int q    = rank >> 5;
    const int rr_  = rank & 31;
    const int tile = (q < 2) ? (63 - rr_) : rr_;
    const int hf   = q & 1;
    const int nt   = tile + 1;
    const int c0k  = (nt + 1) >> 1;
    const int s    = hf ? c0k : 0;        // first 32-key tile of this half
    const int cnt  = hf ? (nt - c0k) : c0k;
    const int R    = (cnt + 1) >> 1;      // 64-key rounds
    const int t0   = tile * 32;

    const size_t bo  = (size_t)b * T_ * H_;
    const size_t vbo = (size_t)b * H_ * T_;

    // Q fragment (B-operand of swapped QK): lane lc holds q-row t0+rg*16+lc
    f16x8 qf[4];
    {
        const size_t qbase = bo + (size_t)(t0 + rg * 16 + lc) * H_;
        #pragma unroll
        for (int kc = 0; kc < 4; ++kc)
            qf[kc] = *(const f16x8*)(qg + qbase + kc * 32 + lg * 8);
    }

    f32x4 Oacc[8];
    #pragma unroll
    for (int ht = 0; ht < 8; ++ht) Oacc[ht] = (f32x4){0.f, 0.f, 0.f, 0.f};
    float m_run = -1e30f;                 // finite sentinel (NaN-free)
    float l_run = 0.f;                    // lane-partial

    f16x8 pf[4];                          // K staging: 16 KB / 256 threads

    #define ISSUE_K(kt0_)                                                     \
        _Pragma("unroll")                                                     \
        for (int it = 0; it < 4; ++it) {                                      \
            const int c = tid + it * 256;                                     \
            const int key = c >> 4, slot = c & 15;                            \
            const int hc = slot ^ (key & 7);                                  \
            pf[it] = *(const f16x8*)(kg + bo                                  \
                      + (size_t)((kt0_) * 32 + key) * H_ + hc * 8);           \
        }

    #define WRITE_K(bf_)                                                      \
        _Pragma("unroll")                                                     \
        for (int it = 0; it < 4; ++it) {                                      \
            const int c = tid + it * 256;                                     \
            const int key = c >> 4, slot = c & 15;                            \
            *(f16x8*)&Kbuf[bf_][key * 128 + slot * 8] = pf[it];               \
        }

    if (R > 0) ISSUE_K(s);

    for (int r = 0; r < R; ++r) {
        const int bf = r & 1;
        WRITE_K(bf);                      // waits vmcnt on pf (compiler)
        __syncthreads();                  // buffer bf ready
        if (r + 1 < R) ISSUE_K(s + 2 * (r + 1));

        const int kt = s + 2 * r + kp;
        if (kt < s + cnt) {
            // ---- V fragments direct from global (issued early) ----
            f16x4 vb[16];
            #pragma unroll
            for (int ct = 0; ct < 2; ++ct)
                #pragma unroll
                for (int ht = 0; ht < 8; ++ht)
                    vb[ct * 8 + ht] = *(const f16x4*)&vtg[vbo
                        + (size_t)(ht * 16 + lc) * T_ + kt * 32 + ct * 16 + lg * 4];

            // ---- S^T = K @ Q^T : two independent accumulator chains ----
            f32x4 sfrA = (f32x4){0.f, 0.f, 0.f, 0.f};
            f32x4 sfrB = (f32x4){0.f, 0.f, 0.f, 0.f};
            f32x4 sfrC = (f32x4){0.f, 0.f, 0.f, 0.f};
            f32x4 sfrD = (f32x4){0.f, 0.f, 0.f, 0.f};
            #pragma unroll
            for (int kc = 0; kc < 4; ++kc) {
                #pragma unroll
                for (int ct = 0; ct < 2; ++ct) {
                    const int key  = kp * 32 + ct * 16 + lc;   // local key row
                    const int slot = (kc * 4 + lg) ^ (key & 7);
                    const f16x8 ka = *(const f16x8*)&Kbuf[bf][key * 128 + slot * 8];
                    if (kc < 2) {
                        if (ct == 0) sfrA = __builtin_amdgcn_mfma_f32_16x16x32_f16(ka, qf[kc], sfrA, 0, 0, 0);
                        else         sfrB = __builtin_amdgcn_mfma_f32_16x16x32_f16(ka, qf[kc], sfrB, 0, 0, 0);
                    } else {
                        if (ct == 0) sfrC = __builtin_amdgcn_mfma_f32_16x16x32_f16(ka, qf[kc], sfrC, 0, 0, 0);
                        else         sfrD = __builtin_amdgcn_mfma_f32_16x16x32_f16(ka, qf[kc], sfrD, 0, 0, 0);
                    }
                }
            }
            f32x4 sfr[2];
            sfr[0] = sfrA + sfrC;
            sfr[1] = sfrB + sfrD;

            // ---- causal mask (diagonal tile only) ----
            if (kt == tile) {
                const int qrow_g = t0 + rg * 16 + lc;
                #pragma unroll
                for (int ct = 0; ct < 2; ++ct)
                    #pragma unroll
                    for (int rr = 0; rr < 4; ++rr) {
                        const int key_g = kt * 32 + ct * 16 + lg * 4 + rr;
                        if (key_g > qrow_g) sfr[ct][rr] = -INFINITY;
                    }
            }

            // ---- softmax: lane-local over 8 regs + 2 shfls ----
            float pmax = sfr[0][0];
            #pragma unroll
            for (int ct = 0; ct < 2; ++ct)
                #pragma unroll
                for (int rr = 0; rr < 4; ++rr) pmax = fmaxf(pmax, sfr[ct][rr]);
            pmax = fmaxf(pmax, __shfl_xor(pmax, 16, 64));
            pmax = fmaxf(pmax, __shfl_xor(pmax, 32, 64));

            if (__any(pmax > m_run)) {
                const float mnew = fmaxf(m_run, pmax);
                const float sc = __expf(m_run - mnew);
                m_run = mnew;
                l_run *= sc;
                float scq[4];
                #pragma unroll
                for (int rr = 0; rr < 4; ++rr)
                    scq[rr] = __shfl(sc, lg * 4 + rr, 64);
                #pragma unroll
                for (int ht = 0; ht < 8; ++ht)
                    #pragma unroll
                    for (int rr = 0; rr < 4; ++rr) Oacc[ht][rr] *= scq[rr];
            }

            // ---- exp + in-lane fp16 pack (P stays in registers) ----
            f16x4 pk[2];
            float lsum = 0.f;
            #pragma unroll
            for (int ct = 0; ct < 2; ++ct)
                #pragma unroll
                for (int rr = 0; rr < 4; ++rr) {
                    const float p = __expf(sfr[ct][rr] - m_run);  // masked->0
                    lsum += p;
                    pk[ct][rr] = (_Float16)p;
                }
            l_run += lsum;

            // ---- PV: 16 independent K=16 MFMAs, V from registers ----
            #pragma unroll
            for (int ht = 0; ht < 8; ++ht)
                #pragma unroll
                for (int ct = 0; ct < 2; ++ct)
                    Oacc[ht] = __builtin_amdgcn_mfma_f32_16x16x16f16(
                        pk[ct], vb[ct * 8 + ht], Oacc[ht], 0, 0, 0);
        }
    }

    // ---- finish lane-partial l ----
    l_run += __shfl_xor(l_run, 16, 64);
    l_run += __shfl_xor(l_run, 32, 64);

    __syncthreads();                      // staging done before aliasing

    // ---- pair combine kp0/kp1; write UNNORMALIZED partial + (m,l) ----
    if (kp == 1) {
        #pragma unroll
        for (int ht = 0; ht < 8; ++ht)
            #pragma unroll
            for (int rr = 0; rr < 4; ++rr)
                Ocmb[(size_t)(rg * 16 + lg * 4 + rr) * 132 + ht * 16 + lc] =
                    Oacc[ht][rr];
        if (lg == 0) {
            Mcmb[(rg * 16 + lc) * 2]     = m_run;
            Mcmb[(rg * 16 + lc) * 2 + 1] = l_run;
        }
    }
    __syncthreads();
    if (kp == 0) {
        const float m1 = Mcmb[(rg * 16 + lc) * 2];
        const float l1 = Mcmb[(rg * 16 + lc) * 2 + 1];
        const float M  = fmaxf(m_run, m1);
        const float a0 = __expf(m_run - M);
        const float a1 = __expf(m1 - M);
        if (lg == 0) {
            pML[(size_t)wg * 64 + (rg * 16 + lc) * 2]     = M;
            pML[(size_t)wg * 64 + (rg * 16 + lc) * 2 + 1] = l_run * a0 + l1 * a1;
        }
        float f0q[4], f1q[4];
        #pragma unroll
        for (int rr = 0; rr < 4; ++rr) {
            f0q[rr] = __shfl(a0, lg * 4 + rr, 64);
            f1q[rr] = __shfl(a1, lg * 4 + rr, 64);
        }
        float* po = pO + (size_t)wg * 4096;
        #pragma unroll
        for (int ht = 0; ht < 8; ++ht)
            #pragma unroll
            for (int rr = 0; rr < 4; ++rr) {
                const float o1 =
                    Ocmb[(size_t)(rg * 16 + lg * 4 + rr) * 132 + ht * 16 + lc];
                po[(size_t)(rg * 16 + lg * 4 + rr) * 128 + ht * 16 + lc] =
                    Oacc[ht][rr] * f0q[rr] + o1 * f1q[rr];
            }
    }
}

// ---------------------------------------------------------------------------
// Kernel 3: attn_merge — combine the two key-halves of each tile.
// grid 512 (= 64 tiles x 8 batches), 256 threads.
// ---------------------------------------------------------------------------
__global__ __launch_bounds__(256) void attn_merge(
    const float* __restrict__ pO, const float* __restrict__ pML,
    float* __restrict__ out)
{
    const int mb   = blockIdx.x;          // 0..511
    const int tile = mb & 63;
    const int b    = mb >> 6;
    const int r    = (tile >= 32) ? (63 - tile) : tile;
    const int rank0 = (tile >= 32) ? r        : (64 + r);
    const int rank1 = (tile >= 32) ? (32 + r) : (96 + r);
    const int j0 = rank0 * 8 + b;
    const int j1 = rank1 * 8 + b;

    const int tid = threadIdx.x;
    const int row = tid >> 3;             // 0..31
    const int cb  = (tid & 7) * 16;       // col start

    const float m0 = pML[(size_t)j0 * 64 + row * 2];
    const float l0 = pML[(size_t)j0 * 64 + row * 2 + 1];
    const float m1 = pML[(size_t)j1 * 64 + row * 2];
    const float l1 = pML[(size_t)j1 * 64 + row * 2 + 1];
    const float M  = fmaxf(m0, m1);
    const float f0 = __expf(m0 - M);
    const float f1 = __expf(m1 - M);
    const float inv = 1.f / (l0 * f0 + l1 * f1);

    const float* o0 = pO + (size_t)j0 * 4096 + row * 128 + cb;
    const float* o1 = pO + (size_t)j1 * 4096 + row * 128 + cb;
    float* ob = out + ((size_t)b * T_ + tile * 32 + row) * H_ + cb;
    #pragma unroll
    for (int i = 0; i < 4; ++i) {
        const f32x4 a = *(const f32x4*)&o0[i * 4];
        const f32x4 c = *(const f32x4*)&o1[i * 4];
        f32x4 v;
        #pragma unroll
        for (int j = 0; j < 4; ++j) v[j] = (a[j] * f0 + c[j] * f1) * inv;
        *(f32x4*)&ob[i * 4] = v;
    }
}

// ---------------------------------------------------------------------------
extern "C" void kernel_launch(void* const* d_in, const int* in_sizes, int n_in,
                              void* d_out, int out_size, void* d_ws, size_t ws_size,
                              hipStream_t stream)
{
    const float* x  = (const float*)d_in[0];
    const float* Wq = (const float*)d_in[1];
    const float* bq = (const float*)d_in[2];
    const float* Wk = (const float*)d_in[3];
    const float* bk = (const float*)d_in[4];
    const float* Wv = (const float*)d_in[5];
    const float* bv = (const float*)d_in[6];
    float* out = (float*)d_out;

    const size_t SZ = (size_t)B_ * T_ * H_;     // 2M elems
    _Float16* qg  = (_Float16*)d_ws;
    _Float16* kg  = qg + SZ;
    _Float16* vg  = kg + SZ;
    _Float16* vtg = vg + SZ;                     // [B][H][T]
    _Float16* Wtf = vtg + SZ;                    // [384][1024]
    float* pO  = (float*)(Wtf + (size_t)384 * C_);   // [1024][32][128]
    float* pML = pO + (size_t)1024 * 4096;           // [1024][32][2]

    wprep<<<dim3(384), dim3(256), 0, stream>>>(Wq, Wk, Wv, Wtf);
    gemm_proj<<<dim3(B_ * T_ / GM, 3), dim3(256), 0, stream>>>(
        x, Wtf, bq, bk, bv, qg, kg, vg);
    vtrans<<<dim3(T_ / 64, H_ / 64, B_), dim3(256), 0, stream>>>(
        (const short*)vg, (short*)vtg);
    attn_v9<<<dim3(1024), dim3(256), 0, stream>>>(qg, kg, vtg, pO, pML);
    attn_merge<<<dim3(512), dim3(256), 0, stream>>>(pO, pML, out);
}

// Round 14
// 88.892 us; speedup vs baseline: 1.4307x; 1.4307x over previous
//
#include <hip/hip_runtime.h>
#include <math.h>

#define B_ 8
#define T_ 2048
#define C_ 1024
#define H_ 128

#define TQA 32           // q rows per attention block (2 row-groups x 16)

#define GM 64            // gemm M-tile
#define GN 128           // gemm N-tile
#define GK 64            // gemm K-tile

typedef __attribute__((ext_vector_type(8))) short s16x8;
typedef __attribute__((ext_vector_type(4))) float f32x4;
typedef __attribute__((ext_vector_type(8))) _Float16 f16x8;
typedef __attribute__((ext_vector_type(4))) _Float16 f16x4;

// ---------------------------------------------------------------------------
// Kernel 0: W prep — transpose W[k][h] (q,k,v) into Wtf[n][k] fp16.
// ---------------------------------------------------------------------------
__global__ __launch_bounds__(256) void wprep(
    const float* __restrict__ Wq, const float* __restrict__ Wk,
    const float* __restrict__ Wv, _Float16* __restrict__ Wtf)
{
    const int n   = blockIdx.x;           // 0..383
    const int mat = n >> 7;
    const int h   = n & 127;
    const float* W = (mat == 0) ? Wq : (mat == 1) ? Wk : Wv;
    for (int k = threadIdx.x; k < C_; k += 256)
        Wtf[(size_t)n * C_ + k] = (_Float16)W[(size_t)k * H_ + h];
}

// ---------------------------------------------------------------------------
// Kernel 1: 2-term fp16 MFMA GEMM (unchanged from round 8).
// ---------------------------------------------------------------------------
__global__ __launch_bounds__(256, 3) void gemm_proj(
    const float* __restrict__ x,
    const _Float16* __restrict__ Wtf,
    const float* __restrict__ bq, const float* __restrict__ bk,
    const float* __restrict__ bv,
    _Float16* __restrict__ qg, _Float16* __restrict__ kg,
    _Float16* __restrict__ vg)
{
    __shared__ _Float16 Ah[GM * GK];      // 8 KB
    __shared__ _Float16 Al[GM * GK];      // 8 KB
    __shared__ _Float16 Bf[GN * GK];      // 16 KB

    const int tid  = threadIdx.x;
    const int my   = blockIdx.y;
    const long m0  = (long)blockIdx.x * GM;
    const int lane = tid & 63;
    const int w    = tid >> 6;
    const int wr   = w >> 1, wc = w & 1;
    const int lg   = lane >> 4, lc = lane & 15;

    float4 xr[4];

    #define LOAD_X(k0)                                                        \
        _Pragma("unroll")                                                     \
        for (int it = 0; it < 4; ++it) {                                      \
            const int i  = tid + it * 256;                                    \
            const int r  = i >> 4;                                            \
            const int k4 = i & 15;                                            \
            xr[it] = *(const float4*)&x[(m0 + r) * C_ + (k0) + k4 * 4];       \
        }

    #define STORE_LDS(k0)                                                     \
        _Pragma("unroll")                                                     \
        for (int it = 0; it < 4; ++it) {                                      \
            const int i  = tid + it * 256;                                    \
            const int r  = i >> 4;                                            \
            const int k4 = i & 15;                                            \
            f16x4 hi4, lo4;                                                   \
            _Pragma("unroll")                                                 \
            for (int j = 0; j < 4; ++j) {                                     \
                const float f = ((const float*)&xr[it])[j];                   \
                const _Float16 h16 = (_Float16)f;                             \
                hi4[j] = h16;                                                 \
                lo4[j] = (_Float16)(f - (float)h16);                          \
            }                                                                 \
            const int off = r * 64 + (((k4 >> 1) ^ (r & 7)) << 3)             \
                          + ((k4 & 1) << 2);                                  \
            *(f16x4*)&Ah[off] = hi4;                                          \
            *(f16x4*)&Al[off] = lo4;                                          \
        }                                                                     \
        _Pragma("unroll")                                                     \
        for (int it = 0; it < 4; ++it) {                                      \
            const int i = tid + it * 256;                                     \
            const int r = i >> 3;                                             \
            const int s = i & 7;                                              \
            const size_t g = (size_t)(my * GN + r) * C_ + (k0) + s * 8;       \
            const int off = r * 64 + ((s ^ (r & 7)) << 3);                    \
            *(f16x8*)&Bf[off] = *(const f16x8*)&Wtf[g];                       \
        }

    f32x4 acc[2][4];
    #pragma unroll
    for (int m = 0; m < 2; ++m)
        #pragma unroll
        for (int n = 0; n < 4; ++n) acc[m][n] = (f32x4){0.f, 0.f, 0.f, 0.f};

    LOAD_X(0);
    STORE_LDS(0);
    __syncthreads();

    for (int kt = 0; kt < C_ / GK; ++kt) {
        if (kt < C_ / GK - 1) LOAD_X((kt + 1) * GK);

        #pragma unroll
        for (int kc = 0; kc < 2; ++kc) {
            f16x8 afh[2], afl[2], bf[4];
            #pragma unroll
            for (int m = 0; m < 2; ++m) {
                const int r = wr * 32 + m * 16 + lc;
                const int off = r * 64 + ((((kc << 2) + lg) ^ (r & 7)) << 3);
                afh[m] = *(const f16x8*)&Ah[off];
                afl[m] = *(const f16x8*)&Al[off];
            }
            #pragma unroll
            for (int n = 0; n < 4; ++n) {
                const int r = wc * 64 + n * 16 + lc;
                const int off = r * 64 + ((((kc << 2) + lg) ^ (r & 7)) << 3);
                bf[n] = *(const f16x8*)&Bf[off];
            }
            #pragma unroll
            for (int m = 0; m < 2; ++m)
                #pragma unroll
                for (int n = 0; n < 4; ++n) {
                    acc[m][n] = __builtin_amdgcn_mfma_f32_16x16x32_f16(afh[m], bf[n], acc[m][n], 0, 0, 0);
                    acc[m][n] = __builtin_amdgcn_mfma_f32_16x16x32_f16(afl[m], bf[n], acc[m][n], 0, 0, 0);
                }
        }
        __syncthreads();
        if (kt < C_ / GK - 1) {
            STORE_LDS((kt + 1) * GK);
            __syncthreads();
        }
    }

    const float* bias = (my == 0) ? bq : (my == 1) ? bk : bv;
    _Float16* og = (my == 0) ? qg : (my == 1) ? kg : vg;

    #pragma unroll
    for (int n = 0; n < 4; ++n) {
        const int h = wc * 64 + n * 16 + lc;
        const float bv_ = bias[h];
        #pragma unroll
        for (int m = 0; m < 2; ++m) {
            #pragma unroll
            for (int rr = 0; rr < 4; ++rr) {
                const long row = m0 + wr * 32 + m * 16 + lg * 4 + rr;
                og[(size_t)row * H_ + h] = (_Float16)(acc[m][n][rr] + bv_);
            }
        }
    }
}

// ---------------------------------------------------------------------------
// Kernel 1b: vtrans — vg [B][T][H] -> vtg [B][H][T] (fp16 bits via short).
// ---------------------------------------------------------------------------
__global__ __launch_bounds__(256) void vtrans(
    const short* __restrict__ vh, short* __restrict__ vtg)
{
    __shared__ short tbuf[64][72];
    const int b  = blockIdx.z;
    const int t0 = blockIdx.x * 64;
    const int h0 = blockIdx.y * 64;
    const int tid = threadIdx.x;
    const size_t bo  = (size_t)b * T_ * H_;
    const size_t vbo = (size_t)b * H_ * T_;

    #pragma unroll
    for (int it = 0; it < 2; ++it) {
        const int u = tid + it * 256;
        const int r = u >> 3, c8 = u & 7;
        *(s16x8*)&tbuf[r][c8 * 8] =
            *(const s16x8*)&vh[bo + (size_t)(t0 + r) * H_ + h0 + c8 * 8];
    }
    __syncthreads();
    #pragma unroll
    for (int it = 0; it < 2; ++it) {
        const int u = tid + it * 256;
        const int t8 = u >> 6, hr = u & 63;
        s16x8 v;
        #pragma unroll
        for (int j = 0; j < 8; ++j) v[j] = tbuf[t8 * 8 + j][hr];
        *(s16x8*)&vtg[vbo + (size_t)(h0 + hr) * T_ + t0 + t8 * 8] = v;
    }
}

// ---------------------------------------------------------------------------
// Kernel 2: causal flash attention v10 = v5 (best measured) with:
//  (a) staging via __builtin_amdgcn_global_load_lds width=16 — LDS dest is
//      LINEAR in chunk id (base + lane*16), swizzle pre-applied on the
//      GLOBAL source address (m173 pattern);  kills pf[] regs + ds_writes.
//  (b) s_setprio(1) around the MFMA clusters (T5; 2 phase-skewed blocks/CU).
// Everything else identical to v5 (45 us measured).
// ---------------------------------------------------------------------------
__global__ __launch_bounds__(256, 2) void attn_v10(
    const _Float16* __restrict__ qg, const _Float16* __restrict__ kg,
    const _Float16* __restrict__ vtg, float* __restrict__ out)
{
    __shared__ __align__(16) short Kbuf[2][64 * 128];   // 32 KB
    __shared__ __align__(16) short Vbuf[2][128 * 64];   // 32 KB
    __shared__ __align__(16) short Pl[4][16 * 40];      // 5 KB

    float* Ocmb = (float*)&Kbuf[0][0];   // [32][132] floats (aliased)
    float* Mcmb = (float*)&Vbuf[0][0];   // [32][2]   floats (aliased)

    const int tid  = threadIdx.x;
    const int lane = tid & 63;
    const int w    = tid >> 6;
    const int rg   = w >> 1;
    const int kp   = w & 1;
    const int lg   = lane >> 4;
    const int lc   = lane & 15;
    const int wg   = blockIdx.x;
    const int rank = wg >> 3;
    const int tile = (rank < 32) ? (63 - rank) : (rank - 32);
    const int b    = wg & 7;
    const int t0   = tile * TQA;

    const size_t bo  = (size_t)b * T_ * H_;
    const size_t vbo = (size_t)b * H_ * T_;

    f16x8 qf[4];
    {
        const size_t qbase = bo + (size_t)(t0 + rg * 16 + lc) * H_;
        #pragma unroll
        for (int kc = 0; kc < 4; ++kc)
            qf[kc] = *(const f16x8*)(qg + qbase + kc * 32 + lg * 8);
    }

    f32x4 Oacc[8];
    #pragma unroll
    for (int ht = 0; ht < 8; ++ht) Oacc[ht] = (f32x4){0.f, 0.f, 0.f, 0.f};
    float m_run = -INFINITY;
    float l_run = 0.f;

    const int nt = tile + 1;
    const int R  = (nt + 1) >> 1;

    // direct global->LDS staging: chunk c = tid + it*256 in [0,2048);
    // c<1024 -> K: dst byte = c*16 (linear), src h-group pre-swizzled.
    // else   -> V: dst byte = (c-1024)*16, src key-group pre-swizzled.
    #define STAGE(bf_, rs0_)                                                  \
        _Pragma("unroll")                                                     \
        for (int it = 0; it < 8; ++it) {                                      \
            const int c = tid + it * 256;                                     \
            if (c < 1024) {                                                   \
                const int key = c >> 4, slot = c & 15;                        \
                const int hc = slot ^ (key & 7);                              \
                const _Float16* src = kg + bo                                 \
                    + (size_t)((rs0_) + key) * H_ + hc * 8;                   \
                __builtin_amdgcn_global_load_lds(                             \
                    (const __attribute__((address_space(1))) void*)src,       \
                    (__attribute__((address_space(3))) void*)&Kbuf[(bf_)][c * 8], \
                    16, 0, 0);                                                \
            } else {                                                          \
                const int cc = c - 1024;                                      \
                const int hh = cc >> 3, slot = cc & 7;                        \
                const int k8 = slot ^ ((hh >> 1) & 7);                        \
                const _Float16* src = vtg + vbo + (size_t)hh * T_             \
                    + (rs0_) + k8 * 8;                                        \
                __builtin_amdgcn_global_load_lds(                             \
                    (const __attribute__((address_space(1))) void*)src,       \
                    (__attribute__((address_space(3))) void*)&Vbuf[(bf_)][cc * 8], \
                    16, 0, 0);                                                \
            }                                                                 \
        }

    STAGE(0, 0);

    for (int r = 0; r < R; ++r) {
        const int bf = r & 1;
        __syncthreads();                  // drains loads into bf; bf ready
        if (r + 1 < R) STAGE(bf ^ 1, (r + 1) * 64);

        const int kt = 2 * r + kp;
        if (kt < nt) {
            f32x4 sfr[2];
            sfr[0] = (f32x4){0.f, 0.f, 0.f, 0.f};
            sfr[1] = (f32x4){0.f, 0.f, 0.f, 0.f};
            __builtin_amdgcn_s_setprio(1);
            #pragma unroll
            for (int kc = 0; kc < 4; ++kc) {
                #pragma unroll
                for (int ct = 0; ct < 2; ++ct) {
                    const int key  = kp * 32 + ct * 16 + lc;
                    const int slot = (kc * 4 + lg) ^ (key & 7);
                    const f16x8 ka = *(const f16x8*)&Kbuf[bf][key * 128 + slot * 8];
                    sfr[ct] = __builtin_amdgcn_mfma_f32_16x16x32_f16(ka, qf[kc], sfr[ct], 0, 0, 0);
                }
            }
            __builtin_amdgcn_s_setprio(0);

            const int qrow_g = t0 + rg * 16 + lc;
            #pragma unroll
            for (int ct = 0; ct < 2; ++ct) {
                #pragma unroll
                for (int rr = 0; rr < 4; ++rr) {
                    const int key_g = kt * 32 + ct * 16 + lg * 4 + rr;
                    if (key_g > qrow_g) sfr[ct][rr] = -INFINITY;
                }
            }

            float pmax = sfr[0][0];
            #pragma unroll
            for (int ct = 0; ct < 2; ++ct)
                #pragma unroll
                for (int rr = 0; rr < 4; ++rr) pmax = fmaxf(pmax, sfr[ct][rr]);
            pmax = fmaxf(pmax, __shfl_xor(pmax, 16, 64));
            pmax = fmaxf(pmax, __shfl_xor(pmax, 32, 64));

            const float mnew = fmaxf(m_run, pmax);
            const float sc = __expf(m_run - mnew);
            m_run = mnew;

            float psum = 0.f;
            #pragma unroll
            for (int ct = 0; ct < 2; ++ct)
                #pragma unroll
                for (int rr = 0; rr < 4; ++rr) {
                    const float p = __expf(sfr[ct][rr] - mnew);
                    sfr[ct][rr] = p;
                    psum += p;
                }
            psum += __shfl_xor(psum, 16, 64);
            psum += __shfl_xor(psum, 32, 64);
            l_run = l_run * sc + psum;

            #pragma unroll
            for (int ct = 0; ct < 2; ++ct) {
                f16x4 pk;
                #pragma unroll
                for (int rr = 0; rr < 4; ++rr) pk[rr] = (_Float16)sfr[ct][rr];
                *(f16x4*)&Pl[w][lc * 40 + ct * 16 + lg * 4] = pk;
            }

            float scq[4];
            #pragma unroll
            for (int rr = 0; rr < 4; ++rr) scq[rr] = __shfl(sc, lg * 4 + rr, 64);
            #pragma unroll
            for (int ht = 0; ht < 8; ++ht)
                #pragma unroll
                for (int rr = 0; rr < 4; ++rr) Oacc[ht][rr] *= scq[rr];

            const f16x8 pa = *(const f16x8*)&Pl[w][lc * 40 + lg * 8];
            __builtin_amdgcn_s_setprio(1);
            #pragma unroll
            for (int ht = 0; ht < 8; ++ht) {
                const int hh   = ht * 16 + lc;
                const int slot = (kp * 4 + lg) ^ ((hh >> 1) & 7);
                const f16x8 vb = *(const f16x8*)&Vbuf[bf][hh * 64 + slot * 8];
                Oacc[ht] = __builtin_amdgcn_mfma_f32_16x16x32_f16(pa, vb, Oacc[ht], 0, 0, 0);
            }
            __builtin_amdgcn_s_setprio(0);
        }
    }

    __syncthreads();                      // all loads drained, rounds done

    if (kp == 1) {
        #pragma unroll
        for (int ht = 0; ht < 8; ++ht)
            #pragma unroll
            for (int rr = 0; rr < 4; ++rr)
                Ocmb[(size_t)(rg * 16 + lg * 4 + rr) * 132 + ht * 16 + lc] =
                    Oacc[ht][rr];
        if (lg == 0) {
            Mcmb[(rg * 16 + lc) * 2]     = m_run;
            Mcmb[(rg * 16 + lc) * 2 + 1] = l_run;
        }
    }
    __syncthreads();
    if (kp == 0) {
        const float m1 = Mcmb[(rg * 16 + lc) * 2];
        const float l1 = Mcmb[(rg * 16 + lc) * 2 + 1];
        const float M  = fmaxf(m_run, m1);
        const float a0 = __expf(m_run - M);
        const float a1 = __expf(m1 - M);
        const float inv = 1.f / (l_run * a0 + l1 * a1);
        const float f0 = a0 * inv, f1 = a1 * inv;
        float f0q[4], f1q[4];
        #pragma unroll
        for (int rr = 0; rr < 4; ++rr) {
            f0q[rr] = __shfl(f0, lg * 4 + rr, 64);
            f1q[rr] = __shfl(f1, lg * 4 + rr, 64);
        }
        float* ob = out + bo + (size_t)(t0 + rg * 16) * H_;
        #pragma unroll
        for (int ht = 0; ht < 8; ++ht)
            #pragma unroll
            for (int rr = 0; rr < 4; ++rr) {
                const float o1 =
                    Ocmb[(size_t)(rg * 16 + lg * 4 + rr) * 132 + ht * 16 + lc];
                ob[(size_t)(lg * 4 + rr) * H_ + ht * 16 + lc] =
                    Oacc[ht][rr] * f0q[rr] + o1 * f1q[rr];
            }
    }
}

// ---------------------------------------------------------------------------
extern "C" void kernel_launch(void* const* d_in, const int* in_sizes, int n_in,
                              void* d_out, int out_size, void* d_ws, size_t ws_size,
                              hipStream_t stream)
{
    const float* x  = (const float*)d_in[0];
    const float* Wq = (const float*)d_in[1];
    const float* bq = (const float*)d_in[2];
    const float* Wk = (const float*)d_in[3];
    const float* bk = (const float*)d_in[4];
    const float* Wv = (const float*)d_in[5];
    const float* bv = (const float*)d_in[6];
    float* out = (float*)d_out;

    const size_t SZ = (size_t)B_ * T_ * H_;     // 2M elems
    _Float16* qg  = (_Float16*)d_ws;
    _Float16* kg  = qg + SZ;
    _Float16* vg  = kg + SZ;
    _Float16* vtg = vg + SZ;                     // [B][H][T]
    _Float16* Wtf = vtg + SZ;                    // [384][1024]

    wprep<<<dim3(384), dim3(256), 0, stream>>>(Wq, Wk, Wv, Wtf);
    gemm_proj<<<dim3(B_ * T_ / GM, 3), dim3(256), 0, stream>>>(
        x, Wtf, bq, bk, bv, qg, kg, vg);
    vtrans<<<dim3(T_ / 64, H_ / 64, B_), dim3(256), 0, stream>>>(
        (const short*)vg, (short*)vtg);
    attn_v10<<<dim3(512), dim3(256), 0, stream>>>(qg, kg, vtg, out);
}

// Round 16
// 82.419 us; speedup vs baseline: 1.5431x; 1.0785x over previous
//
#include <hip/hip_runtime.h>
#include <math.h>

#define B_ 8
#define T_ 2048
#define C_ 1024
#define H_ 128

#define TQA 32           // q rows per attention block (2 row-groups x 16)

#define GM 64            // gemm M-tile
#define GN 128           // gemm N-tile
#define GK 64            // gemm K-tile

#define LOG2E 1.44269504088896340736f

typedef __attribute__((ext_vector_type(8))) short s16x8;
typedef __attribute__((ext_vector_type(4))) float f32x4;
typedef __attribute__((ext_vector_type(8))) _Float16 f16x8;
typedef __attribute__((ext_vector_type(4))) _Float16 f16x4;

// ---------------------------------------------------------------------------
// Kernel 0: W prep — transpose W[k][h] (q,k,v) into Wtf[n][k] fp16.
// Wq is pre-scaled by log2(e) so attn can use exp2 (softmax scale-invariant).
// ---------------------------------------------------------------------------
__global__ __launch_bounds__(256) void wprep(
    const float* __restrict__ Wq, const float* __restrict__ Wk,
    const float* __restrict__ Wv, _Float16* __restrict__ Wtf)
{
    const int n   = blockIdx.x;           // 0..383
    const int mat = n >> 7;
    const int h   = n & 127;
    const float* W = (mat == 0) ? Wq : (mat == 1) ? Wk : Wv;
    const float s = (mat == 0) ? LOG2E : 1.0f;
    for (int k = threadIdx.x; k < C_; k += 256)
        Wtf[(size_t)n * C_ + k] = (_Float16)(W[(size_t)k * H_ + h] * s);
}

// ---------------------------------------------------------------------------
// Kernel 1: fp16 MFMA GEMM. q,k: 2-term hi/lo (softmax-amplified error);
// v: single-term (linear error path, ~0.008 abs — safe) and the epilogue
// writes V TRANSPOSED [B][H][T] directly (f16x4 over 4 consecutive t),
// eliminating the separate vtrans kernel.
// ---------------------------------------------------------------------------
__global__ __launch_bounds__(256, 3) void gemm_proj(
    const float* __restrict__ x,
    const _Float16* __restrict__ Wtf,
    const float* __restrict__ bq, const float* __restrict__ bk,
    const float* __restrict__ bv,
    _Float16* __restrict__ qg, _Float16* __restrict__ kg,
    _Float16* __restrict__ vtg)
{
    __shared__ _Float16 Ah[GM * GK];      // 8 KB
    __shared__ _Float16 Al[GM * GK];      // 8 KB
    __shared__ _Float16 Bf[GN * GK];      // 16 KB

    const int tid  = threadIdx.x;
    const int my   = blockIdx.y;
    const long m0  = (long)blockIdx.x * GM;
    const int lane = tid & 63;
    const int w    = tid >> 6;
    const int wr   = w >> 1, wc = w & 1;
    const int lg   = lane >> 4, lc = lane & 15;
    const bool two_term = (my < 2);

    float4 xr[4];

    #define LOAD_X(k0)                                                        \
        _Pragma("unroll")                                                     \
        for (int it = 0; it < 4; ++it) {                                      \
            const int i  = tid + it * 256;                                    \
            const int r  = i >> 4;                                            \
            const int k4 = i & 15;                                            \
            xr[it] = *(const float4*)&x[(m0 + r) * C_ + (k0) + k4 * 4];       \
        }

    #define STORE_LDS(k0)                                                     \
        _Pragma("unroll")                                                     \
        for (int it = 0; it < 4; ++it) {                                      \
            const int i  = tid + it * 256;                                    \
            const int r  = i >> 4;                                            \
            const int k4 = i & 15;                                            \
            f16x4 hi4, lo4;                                                   \
            _Pragma("unroll")                                                 \
            for (int j = 0; j < 4; ++j) {                                     \
                const float f = ((const float*)&xr[it])[j];                   \
                const _Float16 h16 = (_Float16)f;                             \
                hi4[j] = h16;                                                 \
                lo4[j] = (_Float16)(f - (float)h16);                          \
            }                                                                 \
            const int off = r * 64 + (((k4 >> 1) ^ (r & 7)) << 3)             \
                          + ((k4 & 1) << 2);                                  \
            *(f16x4*)&Ah[off] = hi4;                                          \
            *(f16x4*)&Al[off] = lo4;                                          \
        }                                                                     \
        _Pragma("unroll")                                                     \
        for (int it = 0; it < 4; ++it) {                                      \
            const int i = tid + it * 256;                                     \
            const int r = i >> 3;                                             \
            const int s = i & 7;                                              \
            const size_t g = (size_t)(my * GN + r) * C_ + (k0) + s * 8;       \
            const int off = r * 64 + ((s ^ (r & 7)) << 3);                    \
            *(f16x8*)&Bf[off] = *(const f16x8*)&Wtf[g];                       \
        }

    f32x4 acc[2][4];
    #pragma unroll
    for (int m = 0; m < 2; ++m)
        #pragma unroll
        for (int n = 0; n < 4; ++n) acc[m][n] = (f32x4){0.f, 0.f, 0.f, 0.f};

    LOAD_X(0);
    STORE_LDS(0);
    __syncthreads();

    for (int kt = 0; kt < C_ / GK; ++kt) {
        if (kt < C_ / GK - 1) LOAD_X((kt + 1) * GK);

        #pragma unroll
        for (int kc = 0; kc < 2; ++kc) {
            f16x8 afh[2], afl[2], bf[4];
            #pragma unroll
            for (int m = 0; m < 2; ++m) {
                const int r = wr * 32 + m * 16 + lc;
                const int off = r * 64 + ((((kc << 2) + lg) ^ (r & 7)) << 3);
                afh[m] = *(const f16x8*)&Ah[off];
                afl[m] = *(const f16x8*)&Al[off];
            }
            #pragma unroll
            for (int n = 0; n < 4; ++n) {
                const int r = wc * 64 + n * 16 + lc;
                const int off = r * 64 + ((((kc << 2) + lg) ^ (r & 7)) << 3);
                bf[n] = *(const f16x8*)&Bf[off];
            }
            #pragma unroll
            for (int m = 0; m < 2; ++m)
                #pragma unroll
                for (int n = 0; n < 4; ++n) {
                    acc[m][n] = __builtin_amdgcn_mfma_f32_16x16x32_f16(afh[m], bf[n], acc[m][n], 0, 0, 0);
                    if (two_term)
                        acc[m][n] = __builtin_amdgcn_mfma_f32_16x16x32_f16(afl[m], bf[n], acc[m][n], 0, 0, 0);
                }
        }
        __syncthreads();
        if (kt < C_ / GK - 1) {
            STORE_LDS((kt + 1) * GK);
            __syncthreads();
        }
    }

    if (my < 2) {
        const float* bias = (my == 0) ? bq : bk;
        const float bs = (my == 0) ? LOG2E : 1.0f;
        _Float16* og = (my == 0) ? qg : kg;
        #pragma unroll
        for (int n = 0; n < 4; ++n) {
            const int h = wc * 64 + n * 16 + lc;
            const float bv_ = bias[h] * bs;
            #pragma unroll
            for (int m = 0; m < 2; ++m) {
                #pragma unroll
                for (int rr = 0; rr < 4; ++rr) {
                    const long row = m0 + wr * 32 + m * 16 + lg * 4 + rr;
                    og[(size_t)row * H_ + h] = (_Float16)(acc[m][n][rr] + bv_);
                }
            }
        }
    } else {
        // V: write transposed [B][H][T]; rr = 4 consecutive t -> f16x4 store
        const long b = m0 / T_;
        const long tbase = m0 - b * T_;
        #pragma unroll
        for (int n = 0; n < 4; ++n) {
            const int h = wc * 64 + n * 16 + lc;
            const float bv_ = bv[h];
            #pragma unroll
            for (int m = 0; m < 2; ++m) {
                const long t = tbase + wr * 32 + m * 16 + lg * 4;
                f16x4 pk;
                #pragma unroll
                for (int rr = 0; rr < 4; ++rr)
                    pk[rr] = (_Float16)(acc[m][n][rr] + bv_);
                *(f16x4*)&vtg[((size_t)b * H_ + h) * T_ + t] = pk;
            }
        }
    }
}

// ---------------------------------------------------------------------------
// Kernel 2: causal flash attention v5 (round-8 best, 45.2 us) with exp2
// (q pre-scaled by log2e in wprep).
// ---------------------------------------------------------------------------
__global__ __launch_bounds__(256, 2) void attn_v5(
    const _Float16* __restrict__ qg, const _Float16* __restrict__ kg,
    const _Float16* __restrict__ vtg, float* __restrict__ out)
{
    __shared__ __align__(16) short Kbuf[2][64 * 128];   // 32 KB
    __shared__ __align__(16) short Vbuf[2][128 * 64];   // 32 KB
    __shared__ __align__(16) short Pl[4][16 * 40];      // 5 KB

    float* Ocmb = (float*)&Kbuf[0][0];   // [32][132] floats (aliased)
    float* Mcmb = (float*)&Vbuf[0][0];   // [32][2]   floats (aliased)

    const int tid  = threadIdx.x;
    const int lane = tid & 63;
    const int w    = tid >> 6;
    const int rg   = w >> 1;
    const int kp   = w & 1;
    const int lg   = lane >> 4;
    const int lc   = lane & 15;
    const int wg   = blockIdx.x;
    const int rank = wg >> 3;
    const int tile = (rank < 32) ? (63 - rank) : (rank - 32);
    const int b    = wg & 7;
    const int t0   = tile * TQA;

    const size_t bo  = (size_t)b * T_ * H_;
    const size_t vbo = (size_t)b * H_ * T_;

    f16x8 qf[4];
    {
        const size_t qbase = bo + (size_t)(t0 + rg * 16 + lc) * H_;
        #pragma unroll
        for (int kc = 0; kc < 4; ++kc)
            qf[kc] = *(const f16x8*)(qg + qbase + kc * 32 + lg * 8);
    }

    f32x4 Oacc[8];
    #pragma unroll
    for (int ht = 0; ht < 8; ++ht) Oacc[ht] = (f32x4){0.f, 0.f, 0.f, 0.f};
    float m_run = -INFINITY;
    float l_run = 0.f;

    const int nt = tile + 1;
    const int R  = (nt + 1) >> 1;

    f16x8 pf[8];

    #define ISSUE_ST(rs0_)                                                    \
        _Pragma("unroll")                                                     \
        for (int it = 0; it < 8; ++it) {                                      \
            const int c = tid + it * 256;                                     \
            if (c < 1024) {                                                   \
                const int key = c >> 4, slot = c & 15;                        \
                const int hc = slot ^ (key & 7);                              \
                pf[it] = *(const f16x8*)(kg + bo                              \
                          + (size_t)((rs0_) + key) * H_ + hc * 8);            \
            } else {                                                          \
                const int cc = c - 1024;                                      \
                const int hh = cc >> 3, slot = cc & 7;                        \
                const int k8 = slot ^ ((hh >> 1) & 7);                        \
                pf[it] = *(const f16x8*)(vtg + vbo + (size_t)hh * T_          \
                          + (rs0_) + k8 * 8);                                 \
            }                                                                 \
        }

    #define WRITE_ST(bf_)                                                    \
        _Pragma("unroll")                                                     \
        for (int it = 0; it < 8; ++it) {                                      \
            const int c = tid + it * 256;                                     \
            if (c < 1024) {                                                   \
                const int key = c >> 4, slot = c & 15;                        \
                *(f16x8*)&Kbuf[bf_][key * 128 + slot * 8] = pf[it];           \
            } else {                                                          \
                const int cc = c - 1024;                                      \
                const int hh = cc >> 3, slot = cc & 7;                        \
                *(f16x8*)&Vbuf[bf_][hh * 64 + slot * 8] = pf[it];             \
            }                                                                 \
        }

    ISSUE_ST(0);

    for (int r = 0; r < R; ++r) {
        const int bf = r & 1;
        WRITE_ST(bf);
        __syncthreads();
        if (r + 1 < R) ISSUE_ST((r + 1) * 64);

        const int kt = 2 * r + kp;
        if (kt < nt) {
            f32x4 sfr[2];
            sfr[0] = (f32x4){0.f, 0.f, 0.f, 0.f};
            sfr[1] = (f32x4){0.f, 0.f, 0.f, 0.f};
            #pragma unroll
            for (int kc = 0; kc < 4; ++kc) {
                #pragma unroll
                for (int ct = 0; ct < 2; ++ct) {
                    const int key  = kp * 32 + ct * 16 + lc;
                    const int slot = (kc * 4 + lg) ^ (key & 7);
                    const f16x8 ka = *(const f16x8*)&Kbuf[bf][key * 128 + slot * 8];
                    sfr[ct] = __builtin_amdgcn_mfma_f32_16x16x32_f16(ka, qf[kc], sfr[ct], 0, 0, 0);
                }
            }

            const int qrow_g = t0 + rg * 16 + lc;
            #pragma unroll
            for (int ct = 0; ct < 2; ++ct) {
                #pragma unroll
                for (int rr = 0; rr < 4; ++rr) {
                    const int key_g = kt * 32 + ct * 16 + lg * 4 + rr;
                    if (key_g > qrow_g) sfr[ct][rr] = -INFINITY;
                }
            }

            float pmax = sfr[0][0];
            #pragma unroll
            for (int ct = 0; ct < 2; ++ct)
                #pragma unroll
                for (int rr = 0; rr < 4; ++rr) pmax = fmaxf(pmax, sfr[ct][rr]);
            pmax = fmaxf(pmax, __shfl_xor(pmax, 16, 64));
            pmax = fmaxf(pmax, __shfl_xor(pmax, 32, 64));

            const float mnew = fmaxf(m_run, pmax);
            const float sc = exp2f(m_run - mnew);
            m_run = mnew;

            float psum = 0.f;
            #pragma unroll
            for (int ct = 0; ct < 2; ++ct)
                #pragma unroll
                for (int rr = 0; rr < 4; ++rr) {
                    const float p = exp2f(sfr[ct][rr] - mnew);
                    sfr[ct][rr] = p;
                    psum += p;
                }
            psum += __shfl_xor(psum, 16, 64);
            psum += __shfl_xor(psum, 32, 64);
            l_run = l_run * sc + psum;

            #pragma unroll
            for (int ct = 0; ct < 2; ++ct) {
                f16x4 pk;
                #pragma unroll
                for (int rr = 0; rr < 4; ++rr) pk[rr] = (_Float16)sfr[ct][rr];
                *(f16x4*)&Pl[w][lc * 40 + ct * 16 + lg * 4] = pk;
            }

            float scq[4];
            #pragma unroll
            for (int rr = 0; rr < 4; ++rr) scq[rr] = __shfl(sc, lg * 4 + rr, 64);
            #pragma unroll
            for (int ht = 0; ht < 8; ++ht)
                #pragma unroll
                for (int rr = 0; rr < 4; ++rr) Oacc[ht][rr] *= scq[rr];

            const f16x8 pa = *(const f16x8*)&Pl[w][lc * 40 + lg * 8];
            #pragma unroll
            for (int ht = 0; ht < 8; ++ht) {
                const int hh   = ht * 16 + lc;
                const int slot = (kp * 4 + lg) ^ ((hh >> 1) & 7);
                const f16x8 vb = *(const f16x8*)&Vbuf[bf][hh * 64 + slot * 8];
                Oacc[ht] = __builtin_amdgcn_mfma_f32_16x16x32_f16(pa, vb, Oacc[ht], 0, 0, 0);
            }
        }
    }

    __syncthreads();

    if (kp == 1) {
        #pragma unroll
        for (int ht = 0; ht < 8; ++ht)
            #pragma unroll
            for (int rr = 0; rr < 4; ++rr)
                Ocmb[(size_t)(rg * 16 + lg * 4 + rr) * 132 + ht * 16 + lc] =
                    Oacc[ht][rr];
        if (lg == 0) {
            Mcmb[(rg * 16 + lc) * 2]     = m_run;
            Mcmb[(rg * 16 + lc) * 2 + 1] = l_run;
        }
    }
    __syncthreads();
    if (kp == 0) {
        const float m1 = Mcmb[(rg * 16 + lc) * 2];
        const float l1 = Mcmb[(rg * 16 + lc) * 2 + 1];
        const float M  = fmaxf(m_run, m1);
        const float a0 = exp2f(m_run - M);
        const float a1 = exp2f(m1 - M);
        const float inv = 1.f / (l_run * a0 + l1 * a1);
        const float f0 = a0 * inv, f1 = a1 * inv;
        float f0q[4], f1q[4];
        #pragma unroll
        for (int rr = 0; rr < 4; ++rr) {
            f0q[rr] = __shfl(f0, lg * 4 + rr, 64);
            f1q[rr] = __shfl(f1, lg * 4 + rr, 64);
        }
        float* ob = out + bo + (size_t)(t0 + rg * 16) * H_;
        #pragma unroll
        for (int ht = 0; ht < 8; ++ht)
            #pragma unroll
            for (int rr = 0; rr < 4; ++rr) {
                const float o1 =
                    Ocmb[(size_t)(rg * 16 + lg * 4 + rr) * 132 + ht * 16 + lc];
                ob[(size_t)(lg * 4 + rr) * H_ + ht * 16 + lc] =
                    Oacc[ht][rr] * f0q[rr] + o1 * f1q[rr];
            }
    }
}

// ---------------------------------------------------------------------------
extern "C" void kernel_launch(void* const* d_in, const int* in_sizes, int n_in,
                              void* d_out, int out_size, void* d_ws, size_t ws_size,
                              hipStream_t stream)
{
    const float* x  = (const float*)d_in[0];
    const float* Wq = (const float*)d_in[1];
    const float* bq = (const float*)d_in[2];
    const float* Wk = (const float*)d_in[3];
    const float* bk = (const float*)d_in[4];
    const float* Wv = (const float*)d_in[5];
    const float* bv = (const float*)d_in[6];
    float* out = (float*)d_out;

    const size_t SZ = (size_t)B_ * T_ * H_;     // 2M elems
    _Float16* qg  = (_Float16*)d_ws;
    _Float16* kg  = qg + SZ;
    _Float16* vtg = kg + SZ;                     // [B][H][T]
    _Float16* Wtf = vtg + SZ;                    // [384][1024]

    wprep<<<dim3(384), dim3(256), 0, stream>>>(Wq, Wk, Wv, Wtf);
    gemm_proj<<<dim3(B_ * T_ / GM, 3), dim3(256), 0, stream>>>(
        x, Wtf, bq, bk, bv, qg, kg, vtg);
    attn_v5<<<dim3(512), dim3(256), 0, stream>>>(qg, kg, vtg, out);
}

// Round 17
// 82.078 us; speedup vs baseline: 1.5495x; 1.0042x over previous
//
#include <hip/hip_runtime.h>
#include <math.h>

#define B_ 8
#define T_ 2048
#define C_ 1024
#define H_ 128

#define TQA 32           // q rows per attention block (2 row-groups x 16)

#define GM 64            // gemm M-tile
#define GN 128           // gemm N-tile
#define GK 64            // gemm K-tile

#define LOG2E 1.44269504088896340736f

typedef __attribute__((ext_vector_type(8))) short s16x8;
typedef __attribute__((ext_vector_type(4))) float f32x4;
typedef __attribute__((ext_vector_type(8))) _Float16 f16x8;
typedef __attribute__((ext_vector_type(4))) _Float16 f16x4;

// ---------------------------------------------------------------------------
// Kernel 0: W prep — transpose W[k][h] (q,k,v) into Wtf[n][k] fp16.
// Wq pre-scaled by log2(e) so attn can use exp2 (softmax scale-invariant).
// ---------------------------------------------------------------------------
__global__ __launch_bounds__(256) void wprep(
    const float* __restrict__ Wq, const float* __restrict__ Wk,
    const float* __restrict__ Wv, _Float16* __restrict__ Wtf)
{
    const int n   = blockIdx.x;           // 0..383
    const int mat = n >> 7;
    const int h   = n & 127;
    const float* W = (mat == 0) ? Wq : (mat == 1) ? Wk : Wv;
    const float s = (mat == 0) ? LOG2E : 1.0f;
    for (int k = threadIdx.x; k < C_; k += 256)
        Wtf[(size_t)n * C_ + k] = (_Float16)(W[(size_t)k * H_ + h] * s);
}

// ---------------------------------------------------------------------------
// Kernel 1: fp16 MFMA GEMM. q,k: 2-term hi/lo; v: single-term, transposed
// epilogue. B (W) staging now via global_load_lds width=16: linear LDS dest,
// swizzle pre-applied to the GLOBAL source (dest slot s <- group s^(r&7));
// the read-side XOR cancels it. A staging stays manual (fp32->hi/lo conv).
// ---------------------------------------------------------------------------
__global__ __launch_bounds__(256, 3) void gemm_proj(
    const float* __restrict__ x,
    const _Float16* __restrict__ Wtf,
    const float* __restrict__ bq, const float* __restrict__ bk,
    const float* __restrict__ bv,
    _Float16* __restrict__ qg, _Float16* __restrict__ kg,
    _Float16* __restrict__ vtg)
{
    __shared__ _Float16 Ah[GM * GK];      // 8 KB
    __shared__ _Float16 Al[GM * GK];      // 8 KB
    __shared__ _Float16 Bf[GN * GK];      // 16 KB

    const int tid  = threadIdx.x;
    const int my   = blockIdx.y;
    const long m0  = (long)blockIdx.x * GM;
    const int lane = tid & 63;
    const int w    = tid >> 6;
    const int wr   = w >> 1, wc = w & 1;
    const int lg   = lane >> 4, lc = lane & 15;
    const bool two_term = (my < 2);

    float4 xr[4];

    #define LOAD_X(k0)                                                        \
        _Pragma("unroll")                                                     \
        for (int it = 0; it < 4; ++it) {                                      \
            const int i  = tid + it * 256;                                    \
            const int r  = i >> 4;                                            \
            const int k4 = i & 15;                                            \
            xr[it] = *(const float4*)&x[(m0 + r) * C_ + (k0) + k4 * 4];       \
        }

    // B first (async DMA starts early), then A convert+write.
    #define STORE_LDS(k0)                                                     \
        _Pragma("unroll")                                                     \
        for (int it = 0; it < 4; ++it) {                                      \
            const int i = tid + it * 256;                                     \
            const int r = i >> 3;                                             \
            const int s = i & 7;                                              \
            const int sg = s ^ (r & 7);                                       \
            const _Float16* src = Wtf + (size_t)(my * GN + r) * C_ + (k0)     \
                                + sg * 8;                                     \
            __builtin_amdgcn_global_load_lds(                                 \
                (const __attribute__((address_space(1))) void*)src,           \
                (__attribute__((address_space(3))) void*)&Bf[i * 8],          \
                16, 0, 0);                                                    \
        }                                                                     \
        _Pragma("unroll")                                                     \
        for (int it = 0; it < 4; ++it) {                                      \
            const int i  = tid + it * 256;                                    \
            const int r  = i >> 4;                                            \
            const int k4 = i & 15;                                            \
            f16x4 hi4, lo4;                                                   \
            _Pragma("unroll")                                                 \
            for (int j = 0; j < 4; ++j) {                                     \
                const float f = ((const float*)&xr[it])[j];                   \
                const _Float16 h16 = (_Float16)f;                             \
                hi4[j] = h16;                                                 \
                lo4[j] = (_Float16)(f - (float)h16);                          \
            }                                                                 \
            const int off = r * 64 + (((k4 >> 1) ^ (r & 7)) << 3)             \
                          + ((k4 & 1) << 2);                                  \
            *(f16x4*)&Ah[off] = hi4;                                          \
            *(f16x4*)&Al[off] = lo4;                                          \
        }

    f32x4 acc[2][4];
    #pragma unroll
    for (int m = 0; m < 2; ++m)
        #pragma unroll
        for (int n = 0; n < 4; ++n) acc[m][n] = (f32x4){0.f, 0.f, 0.f, 0.f};

    LOAD_X(0);
    STORE_LDS(0);
    __syncthreads();

    for (int kt = 0; kt < C_ / GK; ++kt) {
        if (kt < C_ / GK - 1) LOAD_X((kt + 1) * GK);

        #pragma unroll
        for (int kc = 0; kc < 2; ++kc) {
            f16x8 afh[2], afl[2], bf[4];
            #pragma unroll
            for (int m = 0; m < 2; ++m) {
                const int r = wr * 32 + m * 16 + lc;
                const int off = r * 64 + ((((kc << 2) + lg) ^ (r & 7)) << 3);
                afh[m] = *(const f16x8*)&Ah[off];
                afl[m] = *(const f16x8*)&Al[off];
            }
            #pragma unroll
            for (int n = 0; n < 4; ++n) {
                const int r = wc * 64 + n * 16 + lc;
                const int off = r * 64 + ((((kc << 2) + lg) ^ (r & 7)) << 3);
                bf[n] = *(const f16x8*)&Bf[off];
            }
            #pragma unroll
            for (int m = 0; m < 2; ++m)
                #pragma unroll
                for (int n = 0; n < 4; ++n) {
                    acc[m][n] = __builtin_amdgcn_mfma_f32_16x16x32_f16(afh[m], bf[n], acc[m][n], 0, 0, 0);
                    if (two_term)
                        acc[m][n] = __builtin_amdgcn_mfma_f32_16x16x32_f16(afl[m], bf[n], acc[m][n], 0, 0, 0);
                }
        }
        __syncthreads();
        if (kt < C_ / GK - 1) {
            STORE_LDS((kt + 1) * GK);
            __syncthreads();
        }
    }

    if (my < 2) {
        const float* bias = (my == 0) ? bq : bk;
        const float bs = (my == 0) ? LOG2E : 1.0f;
        _Float16* og = (my == 0) ? qg : kg;
        #pragma unroll
        for (int n = 0; n < 4; ++n) {
            const int h = wc * 64 + n * 16 + lc;
            const float bv_ = bias[h] * bs;
            #pragma unroll
            for (int m = 0; m < 2; ++m) {
                #pragma unroll
                for (int rr = 0; rr < 4; ++rr) {
                    const long row = m0 + wr * 32 + m * 16 + lg * 4 + rr;
                    og[(size_t)row * H_ + h] = (_Float16)(acc[m][n][rr] + bv_);
                }
            }
        }
    } else {
        // V: write transposed [B][H][T]; rr = 4 consecutive t -> f16x4 store
        const long b = m0 / T_;
        const long tbase = m0 - b * T_;
        #pragma unroll
        for (int n = 0; n < 4; ++n) {
            const int h = wc * 64 + n * 16 + lc;
            const float bv_ = bv[h];
            #pragma unroll
            for (int m = 0; m < 2; ++m) {
                const long t = tbase + wr * 32 + m * 16 + lg * 4;
                f16x4 pk;
                #pragma unroll
                for (int rr = 0; rr < 4; ++rr)
                    pk[rr] = (_Float16)(acc[m][n][rr] + bv_);
                *(f16x4*)&vtg[((size_t)b * H_ + h) * T_ + t] = pk;
            }
        }
    }
}

// ---------------------------------------------------------------------------
// Kernel 2: causal flash attention v5 + defer-max (exact, threshold 0;
// numerics validated in v6/v8) + lane-partial l (2 shfls saved per round).
// ---------------------------------------------------------------------------
__global__ __launch_bounds__(256, 2) void attn_v5(
    const _Float16* __restrict__ qg, const _Float16* __restrict__ kg,
    const _Float16* __restrict__ vtg, float* __restrict__ out)
{
    __shared__ __align__(16) short Kbuf[2][64 * 128];   // 32 KB
    __shared__ __align__(16) short Vbuf[2][128 * 64];   // 32 KB
    __shared__ __align__(16) short Pl[4][16 * 40];      // 5 KB

    float* Ocmb = (float*)&Kbuf[0][0];   // [32][132] floats (aliased)
    float* Mcmb = (float*)&Vbuf[0][0];   // [32][2]   floats (aliased)

    const int tid  = threadIdx.x;
    const int lane = tid & 63;
    const int w    = tid >> 6;
    const int rg   = w >> 1;
    const int kp   = w & 1;
    const int lg   = lane >> 4;
    const int lc   = lane & 15;
    const int wg   = blockIdx.x;
    const int rank = wg >> 3;
    const int tile = (rank < 32) ? (63 - rank) : (rank - 32);
    const int b    = wg & 7;
    const int t0   = tile * TQA;

    const size_t bo  = (size_t)b * T_ * H_;
    const size_t vbo = (size_t)b * H_ * T_;

    f16x8 qf[4];
    {
        const size_t qbase = bo + (size_t)(t0 + rg * 16 + lc) * H_;
        #pragma unroll
        for (int kc = 0; kc < 4; ++kc)
            qf[kc] = *(const f16x8*)(qg + qbase + kc * 32 + lg * 8);
    }

    f32x4 Oacc[8];
    #pragma unroll
    for (int ht = 0; ht < 8; ++ht) Oacc[ht] = (f32x4){0.f, 0.f, 0.f, 0.f};
    float m_run = -INFINITY;
    float l_run = 0.f;                    // lane-partial

    const int nt = tile + 1;
    const int R  = (nt + 1) >> 1;

    f16x8 pf[8];

    #define ISSUE_ST(rs0_)                                                    \
        _Pragma("unroll")                                                     \
        for (int it = 0; it < 8; ++it) {                                      \
            const int c = tid + it * 256;                                     \
            if (c < 1024) {                                                   \
                const int key = c >> 4, slot = c & 15;                        \
                const int hc = slot ^ (key & 7);                              \
                pf[it] = *(const f16x8*)(kg + bo                              \
                          + (size_t)((rs0_) + key) * H_ + hc * 8);            \
            } else {                                                          \
                const int cc = c - 1024;                                      \
                const int hh = cc >> 3, slot = cc & 7;                        \
                const int k8 = slot ^ ((hh >> 1) & 7);                        \
                pf[it] = *(const f16x8*)(vtg + vbo + (size_t)hh * T_          \
                          + (rs0_) + k8 * 8);                                 \
            }                                                                 \
        }

    #define WRITE_ST(bf_)                                                    \
        _Pragma("unroll")                                                     \
        for (int it = 0; it < 8; ++it) {                                      \
            const int c = tid + it * 256;                                     \
            if (c < 1024) {                                                   \
                const int key = c >> 4, slot = c & 15;                        \
                *(f16x8*)&Kbuf[bf_][key * 128 + slot * 8] = pf[it];           \
            } else {                                                          \
                const int cc = c - 1024;                                      \
                const int hh = cc >> 3, slot = cc & 7;                        \
                *(f16x8*)&Vbuf[bf_][hh * 64 + slot * 8] = pf[it];             \
            }                                                                 \
        }

    ISSUE_ST(0);

    for (int r = 0; r < R; ++r) {
        const int bf = r & 1;
        WRITE_ST(bf);
        __syncthreads();
        if (r + 1 < R) ISSUE_ST((r + 1) * 64);

        const int kt = 2 * r + kp;
        if (kt < nt) {
            f32x4 sfr[2];
            sfr[0] = (f32x4){0.f, 0.f, 0.f, 0.f};
            sfr[1] = (f32x4){0.f, 0.f, 0.f, 0.f};
            #pragma unroll
            for (int kc = 0; kc < 4; ++kc) {
                #pragma unroll
                for (int ct = 0; ct < 2; ++ct) {
                    const int key  = kp * 32 + ct * 16 + lc;
                    const int slot = (kc * 4 + lg) ^ (key & 7);
                    const f16x8 ka = *(const f16x8*)&Kbuf[bf][key * 128 + slot * 8];
                    sfr[ct] = __builtin_amdgcn_mfma_f32_16x16x32_f16(ka, qf[kc], sfr[ct], 0, 0, 0);
                }
            }

            const int qrow_g = t0 + rg * 16 + lc;
            #pragma unroll
            for (int ct = 0; ct < 2; ++ct) {
                #pragma unroll
                for (int rr = 0; rr < 4; ++rr) {
                    const int key_g = kt * 32 + ct * 16 + lg * 4 + rr;
                    if (key_g > qrow_g) sfr[ct][rr] = -INFINITY;
                }
            }

            float pmax = sfr[0][0];
            #pragma unroll
            for (int ct = 0; ct < 2; ++ct)
                #pragma unroll
                for (int rr = 0; rr < 4; ++rr) pmax = fmaxf(pmax, sfr[ct][rr]);
            pmax = fmaxf(pmax, __shfl_xor(pmax, 16, 64));
            pmax = fmaxf(pmax, __shfl_xor(pmax, 32, 64));

            // defer-max: rescale only when a new max appears (exact)
            if (__any(pmax > m_run)) {
                const float mnew = fmaxf(m_run, pmax);
                const float sc = exp2f(m_run - mnew);   // 0 on first tile
                m_run = mnew;
                l_run *= sc;
                float scq[4];
                #pragma unroll
                for (int rr = 0; rr < 4; ++rr)
                    scq[rr] = __shfl(sc, lg * 4 + rr, 64);
                #pragma unroll
                for (int ht = 0; ht < 8; ++ht)
                    #pragma unroll
                    for (int rr = 0; rr < 4; ++rr) Oacc[ht][rr] *= scq[rr];
            }

            float psum = 0.f;
            #pragma unroll
            for (int ct = 0; ct < 2; ++ct)
                #pragma unroll
                for (int rr = 0; rr < 4; ++rr) {
                    const float p = exp2f(sfr[ct][rr] - m_run);
                    sfr[ct][rr] = p;
                    psum += p;
                }
            l_run += psum;                // lane-partial; finished at end

            #pragma unroll
            for (int ct = 0; ct < 2; ++ct) {
                f16x4 pk;
                #pragma unroll
                for (int rr = 0; rr < 4; ++rr) pk[rr] = (_Float16)sfr[ct][rr];
                *(f16x4*)&Pl[w][lc * 40 + ct * 16 + lg * 4] = pk;
            }

            const f16x8 pa = *(const f16x8*)&Pl[w][lc * 40 + lg * 8];
            #pragma unroll
            for (int ht = 0; ht < 8; ++ht) {
                const int hh   = ht * 16 + lc;
                const int slot = (kp * 4 + lg) ^ ((hh >> 1) & 7);
                const f16x8 vb = *(const f16x8*)&Vbuf[bf][hh * 64 + slot * 8];
                Oacc[ht] = __builtin_amdgcn_mfma_f32_16x16x32_f16(pa, vb, Oacc[ht], 0, 0, 0);
            }
        }
    }

    // finish lane-partial l (sum the 4 lg groups per qrow)
    l_run += __shfl_xor(l_run, 16, 64);
    l_run += __shfl_xor(l_run, 32, 64);

    __syncthreads();

    if (kp == 1) {
        #pragma unroll
        for (int ht = 0; ht < 8; ++ht)
            #pragma unroll
            for (int rr = 0; rr < 4; ++rr)
                Ocmb[(size_t)(rg * 16 + lg * 4 + rr) * 132 + ht * 16 + lc] =
                    Oacc[ht][rr];
        if (lg == 0) {
            Mcmb[(rg * 16 + lc) * 2]     = m_run;
            Mcmb[(rg * 16 + lc) * 2 + 1] = l_run;
        }
    }
    __syncthreads();
    if (kp == 0) {
        const float m1 = Mcmb[(rg * 16 + lc) * 2];
        const float l1 = Mcmb[(rg * 16 + lc) * 2 + 1];
        const float M  = fmaxf(m_run, m1);
        const float a0 = exp2f(m_run - M);
        const float a1 = exp2f(m1 - M);
        const float inv = 1.f / (l_run * a0 + l1 * a1);
        const float f0 = a0 * inv, f1 = a1 * inv;
        float f0q[4], f1q[4];
        #pragma unroll
        for (int rr = 0; rr < 4; ++rr) {
            f0q[rr] = __shfl(f0, lg * 4 + rr, 64);
            f1q[rr] = __shfl(f1, lg * 4 + rr, 64);
        }
        float* ob = out + bo + (size_t)(t0 + rg * 16) * H_;
        #pragma unroll
        for (int ht = 0; ht < 8; ++ht)
            #pragma unroll
            for (int rr = 0; rr < 4; ++rr) {
                const float o1 =
                    Ocmb[(size_t)(rg * 16 + lg * 4 + rr) * 132 + ht * 16 + lc];
                ob[(size_t)(lg * 4 + rr) * H_ + ht * 16 + lc] =
                    Oacc[ht][rr] * f0q[rr] + o1 * f1q[rr];
            }
    }
}

// ---------------------------------------------------------------------------
extern "C" void kernel_launch(void* const* d_in, const int* in_sizes, int n_in,
                              void* d_out, int out_size, void* d_ws, size_t ws_size,
                              hipStream_t stream)
{
    const float* x  = (const float*)d_in[0];
    const float* Wq = (const float*)d_in[1];
    const float* bq = (const float*)d_in[2];
    const float* Wk = (const float*)d_in[3];
    const float* bk = (const float*)d_in[4];
    const float* Wv = (const float*)d_in[5];
    const float* bv = (const float*)d_in[6];
    float* out = (float*)d_out;

    const size_t SZ = (size_t)B_ * T_ * H_;     // 2M elems
    _Float16* qg  = (_Float16*)d_ws;
    _Float16* kg  = qg + SZ;
    _Float16* vtg = kg + SZ;                     // [B][H][T]
    _Float16* Wtf = vtg + SZ;                    // [384][1024]

    wprep<<<dim3(384), dim3(256), 0, stream>>>(Wq, Wk, Wv, Wtf);
    gemm_proj<<<dim3(B_ * T_ / GM, 3), dim3(256), 0, stream>>>(
        x, Wtf, bq, bk, bv, qg, kg, vtg);
    attn_v5<<<dim3(512), dim3(256), 0, stream>>>(qg, kg, vtg, out);
}

// Round 18
// 79.432 us; speedup vs baseline: 1.6011x; 1.0333x over previous
//
#include <hip/hip_runtime.h>
#include <math.h>

#define B_ 8
#define T_ 2048
#define C_ 1024
#define H_ 128

#define GM 64            // gemm M-tile
#define GN 128           // gemm N-tile
#define GK 64            // gemm K-tile

#define LOG2E 1.44269504088896340736f

typedef __attribute__((ext_vector_type(8))) short s16x8;
typedef __attribute__((ext_vector_type(4))) float f32x4;
typedef __attribute__((ext_vector_type(8))) _Float16 f16x8;
typedef __attribute__((ext_vector_type(4))) _Float16 f16x4;

// ---------------------------------------------------------------------------
// Kernel 0: W prep — transpose W[k][h] (q,k,v) into Wtf[n][k] fp16.
// Wq pre-scaled by log2(e) so attn can use exp2 (softmax scale-invariant).
// ---------------------------------------------------------------------------
__global__ __launch_bounds__(256) void wprep(
    const float* __restrict__ Wq, const float* __restrict__ Wk,
    const float* __restrict__ Wv, _Float16* __restrict__ Wtf)
{
    const int n   = blockIdx.x;           // 0..383
    const int mat = n >> 7;
    const int h   = n & 127;
    const float* W = (mat == 0) ? Wq : (mat == 1) ? Wk : Wv;
    const float s = (mat == 0) ? LOG2E : 1.0f;
    for (int k = threadIdx.x; k < C_; k += 256)
        Wtf[(size_t)n * C_ + k] = (_Float16)(W[(size_t)k * H_ + h] * s);
}

// ---------------------------------------------------------------------------
// Kernel 1: fp16 MFMA GEMM (unchanged from round 17, passed).
// ---------------------------------------------------------------------------
__global__ __launch_bounds__(256, 3) void gemm_proj(
    const float* __restrict__ x,
    const _Float16* __restrict__ Wtf,
    const float* __restrict__ bq, const float* __restrict__ bk,
    const float* __restrict__ bv,
    _Float16* __restrict__ qg, _Float16* __restrict__ kg,
    _Float16* __restrict__ vtg)
{
    __shared__ _Float16 Ah[GM * GK];      // 8 KB
    __shared__ _Float16 Al[GM * GK];      // 8 KB
    __shared__ _Float16 Bf[GN * GK];      // 16 KB

    const int tid  = threadIdx.x;
    const int my   = blockIdx.y;
    const long m0  = (long)blockIdx.x * GM;
    const int lane = tid & 63;
    const int w    = tid >> 6;
    const int wr   = w >> 1, wc = w & 1;
    const int lg   = lane >> 4, lc = lane & 15;
    const bool two_term = (my < 2);

    float4 xr[4];

    #define LOAD_X(k0)                                                        \
        _Pragma("unroll")                                                     \
        for (int it = 0; it < 4; ++it) {                                      \
            const int i  = tid + it * 256;                                    \
            const int r  = i >> 4;                                            \
            const int k4 = i & 15;                                            \
            xr[it] = *(const float4*)&x[(m0 + r) * C_ + (k0) + k4 * 4];       \
        }

    #define STORE_LDS(k0)                                                     \
        _Pragma("unroll")                                                     \
        for (int it = 0; it < 4; ++it) {                                      \
            const int i = tid + it * 256;                                     \
            const int r = i >> 3;                                             \
            const int s = i & 7;                                              \
            const int sg = s ^ (r & 7);                                       \
            const _Float16* src = Wtf + (size_t)(my * GN + r) * C_ + (k0)     \
                                + sg * 8;                                     \
            __builtin_amdgcn_global_load_lds(                                 \
                (const __attribute__((address_space(1))) void*)src,           \
                (__attribute__((address_space(3))) void*)&Bf[i * 8],          \
                16, 0, 0);                                                    \
        }                                                                     \
        _Pragma("unroll")                                                     \
        for (int it = 0; it < 4; ++it) {                                      \
            const int i  = tid + it * 256;                                    \
            const int r  = i >> 4;                                            \
            const int k4 = i & 15;                                            \
            f16x4 hi4, lo4;                                                   \
            _Pragma("unroll")                                                 \
            for (int j = 0; j < 4; ++j) {                                     \
                const float f = ((const float*)&xr[it])[j];                   \
                const _Float16 h16 = (_Float16)f;                             \
                hi4[j] = h16;                                                 \
                lo4[j] = (_Float16)(f - (float)h16);                          \
            }                                                                 \
            const int off = r * 64 + (((k4 >> 1) ^ (r & 7)) << 3)             \
                          + ((k4 & 1) << 2);                                  \
            *(f16x4*)&Ah[off] = hi4;                                          \
            *(f16x4*)&Al[off] = lo4;                                          \
        }

    f32x4 acc[2][4];
    #pragma unroll
    for (int m = 0; m < 2; ++m)
        #pragma unroll
        for (int n = 0; n < 4; ++n) acc[m][n] = (f32x4){0.f, 0.f, 0.f, 0.f};

    LOAD_X(0);
    STORE_LDS(0);
    __syncthreads();

    for (int kt = 0; kt < C_ / GK; ++kt) {
        if (kt < C_ / GK - 1) LOAD_X((kt + 1) * GK);

        #pragma unroll
        for (int kc = 0; kc < 2; ++kc) {
            f16x8 afh[2], afl[2], bf[4];
            #pragma unroll
            for (int m = 0; m < 2; ++m) {
                const int r = wr * 32 + m * 16 + lc;
                const int off = r * 64 + ((((kc << 2) + lg) ^ (r & 7)) << 3);
                afh[m] = *(const f16x8*)&Ah[off];
                afl[m] = *(const f16x8*)&Al[off];
            }
            #pragma unroll
            for (int n = 0; n < 4; ++n) {
                const int r = wc * 64 + n * 16 + lc;
                const int off = r * 64 + ((((kc << 2) + lg) ^ (r & 7)) << 3);
                bf[n] = *(const f16x8*)&Bf[off];
            }
            #pragma unroll
            for (int m = 0; m < 2; ++m)
                #pragma unroll
                for (int n = 0; n < 4; ++n) {
                    acc[m][n] = __builtin_amdgcn_mfma_f32_16x16x32_f16(afh[m], bf[n], acc[m][n], 0, 0, 0);
                    if (two_term)
                        acc[m][n] = __builtin_amdgcn_mfma_f32_16x16x32_f16(afl[m], bf[n], acc[m][n], 0, 0, 0);
                }
        }
        __syncthreads();
        if (kt < C_ / GK - 1) {
            STORE_LDS((kt + 1) * GK);
            __syncthreads();
        }
    }

    if (my < 2) {
        const float* bias = (my == 0) ? bq : bk;
        const float bs = (my == 0) ? LOG2E : 1.0f;
        _Float16* og = (my == 0) ? qg : kg;
        #pragma unroll
        for (int n = 0; n < 4; ++n) {
            const int h = wc * 64 + n * 16 + lc;
            const float bv_ = bias[h] * bs;
            #pragma unroll
            for (int m = 0; m < 2; ++m) {
                #pragma unroll
                for (int rr = 0; rr < 4; ++rr) {
                    const long row = m0 + wr * 32 + m * 16 + lg * 4 + rr;
                    og[(size_t)row * H_ + h] = (_Float16)(acc[m][n][rr] + bv_);
                }
            }
        }
    } else {
        const long b = m0 / T_;
        const long tbase = m0 - b * T_;
        #pragma unroll
        for (int n = 0; n < 4; ++n) {
            const int h = wc * 64 + n * 16 + lc;
            const float bv_ = bv[h];
            #pragma unroll
            for (int m = 0; m < 2; ++m) {
                const long t = tbase + wr * 32 + m * 16 + lg * 4;
                f16x4 pk;
                #pragma unroll
                for (int rr = 0; rr < 4; ++rr)
                    pk[rr] = (_Float16)(acc[m][n][rr] + bv_);
                *(f16x4*)&vtg[((size_t)b * H_ + h) * T_ + t] = pk;
            }
        }
    }
}

// ---------------------------------------------------------------------------
// Kernel 2: attn_v11 — r17 attn body (byte-identical staging/QKT/softmax/PV)
// with SPLIT-K jobs: grid 1024; rank = wg>>3 (0..127), tile = 63-(rank>>1)
// (LPT: biggest first), hf = rank&1 selects the round-range half. Max job =
// 16 rounds (vs 32) -> latency-chain makespan halves. Jobs emit unnormalized
// partials (pO, pML) per v9's validated scheme; attn_merge combines halves.
// ---------------------------------------------------------------------------
__global__ __launch_bounds__(256, 2) void attn_v11(
    const _Float16* __restrict__ qg, const _Float16* __restrict__ kg,
    const _Float16* __restrict__ vtg, float* __restrict__ pO,
    float* __restrict__ pML)
{
    __shared__ __align__(16) short Kbuf[2][64 * 128];   // 32 KB
    __shared__ __align__(16) short Vbuf[2][128 * 64];   // 32 KB
    __shared__ __align__(16) short Pl[4][16 * 40];      // 5 KB

    float* Ocmb = (float*)&Kbuf[0][0];   // [32][132] floats (aliased)
    float* Mcmb = (float*)&Vbuf[0][0];   // [32][2]   floats (aliased)

    const int tid  = threadIdx.x;
    const int lane = tid & 63;
    const int w    = tid >> 6;
    const int rg   = w >> 1;
    const int kp   = w & 1;
    const int lg   = lane >> 4;
    const int lc   = lane & 15;
    const int wg   = blockIdx.x;          // 0..1023
    const int rank = wg >> 3;
    const int b    = wg & 7;
    const int tile = 63 - (rank >> 1);
    const int hf   = rank & 1;
    const int t0   = tile * 32;
    const int nt   = tile + 1;            // 32-key tiles
    const int Rt   = (nt + 1) >> 1;       // total 64-key rounds
    const int Ra   = (Rt + 1) >> 1;
    const int r0   = hf ? Ra : 0;
    const int r1   = hf ? Rt : Ra;

    const size_t bo  = (size_t)b * T_ * H_;
    const size_t vbo = (size_t)b * H_ * T_;

    f16x8 qf[4];
    {
        const size_t qbase = bo + (size_t)(t0 + rg * 16 + lc) * H_;
        #pragma unroll
        for (int kc = 0; kc < 4; ++kc)
            qf[kc] = *(const f16x8*)(qg + qbase + kc * 32 + lg * 8);
    }

    f32x4 Oacc[8];
    #pragma unroll
    for (int ht = 0; ht < 8; ++ht) Oacc[ht] = (f32x4){0.f, 0.f, 0.f, 0.f};
    float m_run = -1e30f;                 // finite sentinel (empty-job safe)
    float l_run = 0.f;                    // lane-partial

    f16x8 pf[8];

    #define ISSUE_ST(rs0_)                                                    \
        _Pragma("unroll")                                                     \
        for (int it = 0; it < 8; ++it) {                                      \
            const int c = tid + it * 256;                                     \
            if (c < 1024) {                                                   \
                const int key = c >> 4, slot = c & 15;                        \
                const int hc = slot ^ (key & 7);                              \
                pf[it] = *(const f16x8*)(kg + bo                              \
                          + (size_t)((rs0_) + key) * H_ + hc * 8);            \
            } else {                                                          \
                const int cc = c - 1024;                                      \
                const int hh = cc >> 3, slot = cc & 7;                        \
                const int k8 = slot ^ ((hh >> 1) & 7);                        \
                pf[it] = *(const f16x8*)(vtg + vbo + (size_t)hh * T_          \
                          + (rs0_) + k8 * 8);                                 \
            }                                                                 \
        }

    #define WRITE_ST(bf_)                                                    \
        _Pragma("unroll")                                                     \
        for (int it = 0; it < 8; ++it) {                                      \
            const int c = tid + it * 256;                                     \
            if (c < 1024) {                                                   \
                const int key = c >> 4, slot = c & 15;                        \
                *(f16x8*)&Kbuf[bf_][key * 128 + slot * 8] = pf[it];           \
            } else {                                                          \
                const int cc = c - 1024;                                      \
                const int hh = cc >> 3, slot = cc & 7;                        \
                *(f16x8*)&Vbuf[bf_][hh * 64 + slot * 8] = pf[it];             \
            }                                                                 \
        }

    if (r0 < r1) ISSUE_ST(r0 * 64);

    for (int r = r0; r < r1; ++r) {
        const int bf = (r - r0) & 1;
        WRITE_ST(bf);
        __syncthreads();
        if (r + 1 < r1) ISSUE_ST((r + 1) * 64);

        const int kt = 2 * r + kp;
        if (kt < nt) {
            f32x4 sfr[2];
            sfr[0] = (f32x4){0.f, 0.f, 0.f, 0.f};
            sfr[1] = (f32x4){0.f, 0.f, 0.f, 0.f};
            #pragma unroll
            for (int kc = 0; kc < 4; ++kc) {
                #pragma unroll
                for (int ct = 0; ct < 2; ++ct) {
                    const int key  = kp * 32 + ct * 16 + lc;
                    const int slot = (kc * 4 + lg) ^ (key & 7);
                    const f16x8 ka = *(const f16x8*)&Kbuf[bf][key * 128 + slot * 8];
                    sfr[ct] = __builtin_amdgcn_mfma_f32_16x16x32_f16(ka, qf[kc], sfr[ct], 0, 0, 0);
                }
            }

            const int qrow_g = t0 + rg * 16 + lc;
            #pragma unroll
            for (int ct = 0; ct < 2; ++ct) {
                #pragma unroll
                for (int rr = 0; rr < 4; ++rr) {
                    const int key_g = kt * 32 + ct * 16 + lg * 4 + rr;
                    if (key_g > qrow_g) sfr[ct][rr] = -INFINITY;
                }
            }

            float pmax = sfr[0][0];
            #pragma unroll
            for (int ct = 0; ct < 2; ++ct)
                #pragma unroll
                for (int rr = 0; rr < 4; ++rr) pmax = fmaxf(pmax, sfr[ct][rr]);
            pmax = fmaxf(pmax, __shfl_xor(pmax, 16, 64));
            pmax = fmaxf(pmax, __shfl_xor(pmax, 32, 64));

            if (__any(pmax > m_run)) {
                const float mnew = fmaxf(m_run, pmax);
                const float sc = exp2f(m_run - mnew);
                m_run = mnew;
                l_run *= sc;
                float scq[4];
                #pragma unroll
                for (int rr = 0; rr < 4; ++rr)
                    scq[rr] = __shfl(sc, lg * 4 + rr, 64);
                #pragma unroll
                for (int ht = 0; ht < 8; ++ht)
                    #pragma unroll
                    for (int rr = 0; rr < 4; ++rr) Oacc[ht][rr] *= scq[rr];
            }

            float psum = 0.f;
            #pragma unroll
            for (int ct = 0; ct < 2; ++ct)
                #pragma unroll
                for (int rr = 0; rr < 4; ++rr) {
                    const float p = exp2f(sfr[ct][rr] - m_run);
                    sfr[ct][rr] = p;
                    psum += p;
                }
            l_run += psum;

            #pragma unroll
            for (int ct = 0; ct < 2; ++ct) {
                f16x4 pk;
                #pragma unroll
                for (int rr = 0; rr < 4; ++rr) pk[rr] = (_Float16)sfr[ct][rr];
                *(f16x4*)&Pl[w][lc * 40 + ct * 16 + lg * 4] = pk;
            }

            const f16x8 pa = *(const f16x8*)&Pl[w][lc * 40 + lg * 8];
            #pragma unroll
            for (int ht = 0; ht < 8; ++ht) {
                const int hh   = ht * 16 + lc;
                const int slot = (kp * 4 + lg) ^ ((hh >> 1) & 7);
                const f16x8 vb = *(const f16x8*)&Vbuf[bf][hh * 64 + slot * 8];
                Oacc[ht] = __builtin_amdgcn_mfma_f32_16x16x32_f16(pa, vb, Oacc[ht], 0, 0, 0);
            }
        }
    }

    // finish lane-partial l (sum the 4 lg groups per qrow)
    l_run += __shfl_xor(l_run, 16, 64);
    l_run += __shfl_xor(l_run, 32, 64);

    __syncthreads();                      // rounds done before aliasing

    // pair combine kp0/kp1; write UNNORMALIZED partial + (M, L)
    if (kp == 1) {
        #pragma unroll
        for (int ht = 0; ht < 8; ++ht)
            #pragma unroll
            for (int rr = 0; rr < 4; ++rr)
                Ocmb[(size_t)(rg * 16 + lg * 4 + rr) * 132 + ht * 16 + lc] =
                    Oacc[ht][rr];
        if (lg == 0) {
            Mcmb[(rg * 16 + lc) * 2]     = m_run;
            Mcmb[(rg * 16 + lc) * 2 + 1] = l_run;
        }
    }
    __syncthreads();
    if (kp == 0) {
        const float m1 = Mcmb[(rg * 16 + lc) * 2];
        const float l1 = Mcmb[(rg * 16 + lc) * 2 + 1];
        const float M  = fmaxf(m_run, m1);
        const float a0 = exp2f(m_run - M);
        const float a1 = exp2f(m1 - M);
        if (lg == 0) {
            pML[(size_t)wg * 64 + (rg * 16 + lc) * 2]     = M;
            pML[(size_t)wg * 64 + (rg * 16 + lc) * 2 + 1] = l_run * a0 + l1 * a1;
        }
        float f0q[4], f1q[4];
        #pragma unroll
        for (int rr = 0; rr < 4; ++rr) {
            f0q[rr] = __shfl(a0, lg * 4 + rr, 64);
            f1q[rr] = __shfl(a1, lg * 4 + rr, 64);
        }
        float* po = pO + (size_t)wg * 4096;
        #pragma unroll
        for (int ht = 0; ht < 8; ++ht)
            #pragma unroll
            for (int rr = 0; rr < 4; ++rr) {
                const float o1 =
                    Ocmb[(size_t)(rg * 16 + lg * 4 + rr) * 132 + ht * 16 + lc];
                po[(size_t)(rg * 16 + lg * 4 + rr) * 128 + ht * 16 + lc] =
                    Oacc[ht][rr] * f0q[rr] + o1 * f1q[rr];
            }
    }
}

// ---------------------------------------------------------------------------
// Kernel 3: attn_merge — combine the two key-halves of each tile.
// grid 512 (= 64 tiles x 8 batches), 256 threads.
// ---------------------------------------------------------------------------
__global__ __launch_bounds__(256) void attn_merge(
    const float* __restrict__ pO, const float* __restrict__ pML,
    float* __restrict__ out)
{
    const int mb   = blockIdx.x;          // 0..511
    const int tile = mb & 63;
    const int b    = mb >> 6;
    const int j0 = (2 * (63 - tile))     * 8 + b;
    const int j1 = (2 * (63 - tile) + 1) * 8 + b;

    const int tid = threadIdx.x;
    const int row = tid >> 3;             // 0..31
    const int cb  = (tid & 7) * 16;       // col start

    const float m0 = pML[(size_t)j0 * 64 + row * 2];
    const float l0 = pML[(size_t)j0 * 64 + row * 2 + 1];
    const float m1 = pML[(size_t)j1 * 64 + row * 2];
    const float l1 = pML[(size_t)j1 * 64 + row * 2 + 1];
    const float M  = fmaxf(m0, m1);
    const float f0 = exp2f(m0 - M);
    const float f1 = exp2f(m1 - M);
    const float inv = 1.f / (l0 * f0 + l1 * f1);

    const float* o0 = pO + (size_t)j0 * 4096 + row * 128 + cb;
    const float* o1 = pO + (size_t)j1 * 4096 + row * 128 + cb;
    float* ob = out + ((size_t)b * T_ + tile * 32 + row) * H_ + cb;
    #pragma unroll
    for (int i = 0; i < 4; ++i) {
        const f32x4 a = *(const f32x4*)&o0[i * 4];
        const f32x4 c = *(const f32x4*)&o1[i * 4];
        f32x4 v;
        #pragma unroll
        for (int j = 0; j < 4; ++j) v[j] = (a[j] * f0 + c[j] * f1) * inv;
        *(f32x4*)&ob[i * 4] = v;
    }
}

// ---------------------------------------------------------------------------
extern "C" void kernel_launch(void* const* d_in, const int* in_sizes, int n_in,
                              void* d_out, int out_size, void* d_ws, size_t ws_size,
                              hipStream_t stream)
{
    const float* x  = (const float*)d_in[0];
    const float* Wq = (const float*)d_in[1];
    const float* bq = (const float*)d_in[2];
    const float* Wk = (const float*)d_in[3];
    const float* bk = (const float*)d_in[4];
    const float* Wv = (const float*)d_in[5];
    const float* bv = (const float*)d_in[6];
    float* out = (float*)d_out;

    const size_t SZ = (size_t)B_ * T_ * H_;     // 2M elems
    _Float16* qg  = (_Float16*)d_ws;
    _Float16* kg  = qg + SZ;
    _Float16* vtg = kg + SZ;                     // [B][H][T]
    _Float16* Wtf = vtg + SZ;                    // [384][1024]
    float* pO  = (float*)(Wtf + (size_t)384 * C_);   // [1024][32][128]
    float* pML = pO + (size_t)1024 * 4096;           // [1024][32][2]

    wprep<<<dim3(384), dim3(256), 0, stream>>>(Wq, Wk, Wv, Wtf);
    gemm_proj<<<dim3(B_ * T_ / GM, 3), dim3(256), 0, stream>>>(
        x, Wtf, bq, bk, bv, qg, kg, vtg);
    attn_v11<<<dim3(1024), dim3(256), 0, stream>>>(qg, kg, vtg, pO, pML);
    attn_merge<<<dim3(512), dim3(256), 0, stream>>>(pO, pML, out);
}